// Round 8
// baseline (72.583 us; speedup 1.0000x reference)
//
#include <hip/hip_runtime.h>
#include <hip/hip_bf16.h>

#define BSZ   4096
#define NCON  8192
#define DFEAT 256
#define C2    20.60992914f    // (1/0.07) * log2(e) : logits-minus-max in log2 units
#define LN2   0.6931471806f

#define BJ 64    // block tile in j (contrast) — staged in LDS
#define BI 128   // block tile in i (anchor) — 4 waves x 32 rows, in registers

typedef __attribute__((ext_vector_type(8))) short short8;
typedef __attribute__((ext_vector_type(4))) float f32x4;

__device__ __forceinline__ unsigned short f2bf(float f) {
    __hip_bfloat16 h = __float2bfloat16(f);
    return *reinterpret_cast<unsigned short*>(&h);
}

__device__ __forceinline__ void gload_lds16(const void* g, void* l) {
    __builtin_amdgcn_global_load_lds(
        (const __attribute__((address_space(1))) unsigned int*)g,
        (__attribute__((address_space(3))) unsigned int*)l,
        16, 0, 0);
}

// ws layout: [0, 4MB) contrast bf16 [NCON][DFEAT]; then f32 S[4096], A[4096], B[4096]

__global__ __launch_bounds__(256) void k_prep(const float* __restrict__ feat,
                                              unsigned short* __restrict__ con,
                                              float* __restrict__ acc) {
    int idx = blockIdx.x * 256 + threadIdx.x;
    int e = idx * 4;
    int j = e >> 8;
    int k = e & 255;
    int src = (j < BSZ) ? ((j * 2) * DFEAT + k)
                        : (((j - BSZ) * 2 + 1) * DFEAT + k);
    float4 f = *(const float4*)(feat + src);
    ushort4 o;
    o.x = f2bf(f.x); o.y = f2bf(f.y); o.z = f2bf(f.z); o.w = f2bf(f.w);
    *(ushort4*)(con + e) = o;
    if (idx < 3 * BSZ) acc[idx] = 0.0f;
}

// lX layout: 4 sub-panels [k2][row 0..63][64 cols], 128B row stride —
// bit-identical to the round-4/5 pattern that measured 0 bank conflicts.
__global__ __launch_bounds__(256) void k_main(const __hip_bfloat16* __restrict__ conp,
                                              const float* __restrict__ va,
                                              const int* __restrict__ dia,
                                              const int* __restrict__ thr_ptr,
                                              float* __restrict__ Srow,
                                              float* __restrict__ Arow,
                                              float* __restrict__ Brow) {
    __shared__ short lX[BJ * DFEAT];            // 32 KB total
    __shared__ float s_vjx[BJ], s_vjy[BJ];
    __shared__ int   s_dj[BJ];

    const int tid  = threadIdx.x;
    const int lane = tid & 63;
    const int wv   = tid >> 6;
    const int l15  = lane & 15;
    const int hi   = lane >> 4;
    const int jbase = blockIdx.x * BJ;              // [0, 8192)
    const int ibase = blockIdx.y * BI + wv * 32;    // this wave's 32 anchor rows
    const short* cs = (const short*)conp;

    // ---- stage X panel: linear LDS dest, inverse-swizzled global source ----
    #pragma unroll
    for (int q = 0; q < 8; ++q) {
        int e   = q * 2048 + tid * 8;      // element in [0, 16384)
        int col = e & 63;
        int row = (e >> 6) & 63;
        int k2  = e >> 12;                 // which 64-col sub-panel
        int scol = col ^ ((row & 7) << 3); // element-space involution (8-elem granules)
        gload_lds16(cs + (size_t)(jbase + row) * DFEAT + k2 * 64 + scol, &lX[e]);
    }

    // ---- Y panel straight to registers: 32 rows x 256 K = 64 VGPRs, static index ----
    const short* yrow0 = cs + (size_t)(ibase + l15) * DFEAT + hi * 8;
    short8 y[2][8];
    #pragma unroll
    for (int n = 0; n < 2; ++n)
        #pragma unroll
        for (int s = 0; s < 8; ++s)
            y[n][s] = *(const short8*)(yrow0 + (size_t)n * 16 * DFEAT + s * 32);

    if (tid < BJ) {
        int jm = (jbase + tid) & (BSZ - 1);
        s_vjx[tid] = va[2 * jm]; s_vjy[tid] = va[2 * jm + 1]; s_dj[tid] = dia[jm];
    }

    int raw = *thr_ptr;
    float t_ = (raw > 0 && raw < 100000) ? (float)raw : __int_as_float(raw);
    float thres2 = t_ * t_;

    f32x4 acc[4][2];   // [m = j-frag][n = i-frag]
    #pragma unroll
    for (int m = 0; m < 4; ++m)
        #pragma unroll
        for (int n = 0; n < 2; ++n)
            acc[m][n] = (f32x4){0.f, 0.f, 0.f, 0.f};

    __syncthreads();   // the only barrier: staging + Y loads drained

    // ---- straight-line K stream: 8 steps x (4 ds_read_b128 + 8 MFMA), no syncs ----
    #pragma unroll
    for (int s = 0; s < 8; ++s) {
        const int base = (s >> 1) * 8192;                    // sub-panel byte base
        const int colb = (s & 1) * 64 + hi * 16;             // byte col in sub-panel
        short8 xf[4];
        #pragma unroll
        for (int m = 0; m < 4; ++m) {
            int row = m * 16 + l15;
            xf[m] = *(const short8*)((const char*)lX + base + row * 128 + (colb ^ ((row & 7) << 4)));
        }
        #pragma unroll
        for (int m = 0; m < 4; ++m)
            #pragma unroll
            for (int n = 0; n < 2; ++n)
                acc[m][n] = __builtin_amdgcn_mfma_f32_16x16x32_bf16(xf[m], y[n][s], acc[m][n], 0, 0, 0);
    }

    // ---- epilogue: D[j][i]; lane holds j = m*16 + hi*4 + r, i = n*16 + l15 ----
    float vix[2], viy[2]; int di[2];
    #pragma unroll
    for (int n = 0; n < 2; ++n) {
        int i = ibase + n * 16 + l15;
        vix[n] = va[2 * i]; viy[n] = va[2 * i + 1]; di[n] = dia[i];
    }

    float sp[2] = {0.f, 0.f};
    float ap[2] = {0.f, 0.f};   // accumulated in log2 units
    float bp[2] = {0.f, 0.f};

    #pragma unroll
    for (int m = 0; m < 4; ++m) {
        #pragma unroll
        for (int r = 0; r < 4; ++r) {
            const int jl = m * 16 + hi * 4 + r;
            const int j  = jbase + jl;
            const int jm = j & (BSZ - 1);
            float vjx = s_vjx[jl], vjy = s_vjy[jl];
            int dj = s_dj[jl];
            #pragma unroll
            for (int n = 0; n < 2; ++n) {
                const int i = ibase + n * 16 + l15;
                float l2 = __builtin_fmaf(acc[m][n][r], C2, -C2);   // (dot-1)/T in log2
                bool lm = (j != i);
                float e = lm ? exp2f(l2) : 0.0f;
                float dx = vix[n] - vjx, dy = viy[n] - vjy;
                bool mk = (i == jm) | (di[n] == dj) | (dx * dx + dy * dy < thres2);
                sp[n] += e;
                if (mk & lm) { ap[n] += l2; bp[n] += 1.0f; }
            }
        }
    }

    #pragma unroll
    for (int n = 0; n < 2; ++n) {
        float s = sp[n], a = ap[n], b = bp[n];
        s += __shfl_xor(s, 16, 64);  a += __shfl_xor(a, 16, 64);  b += __shfl_xor(b, 16, 64);
        s += __shfl_xor(s, 32, 64);  a += __shfl_xor(a, 32, 64);  b += __shfl_xor(b, 32, 64);
        if (hi == 0) {
            int i = ibase + n * 16 + l15;
            atomicAdd(&Srow[i], s);
            atomicAdd(&Arow[i], a * LN2);   // back to natural-log units
            atomicAdd(&Brow[i], b);
        }
    }
}

__global__ __launch_bounds__(256) void k_final(const float* __restrict__ S,
                                               const float* __restrict__ A,
                                               const float* __restrict__ B,
                                               float* __restrict__ out) {
    __shared__ float red[256];
    float sum = 0.f;
    for (int i = threadIdx.x; i < BSZ; i += 256) {
        float b = B[i];
        float v = (A[i] - b * logf(S[i] + 1e-10f)) / (b + 1e-10f);
        sum += -v;
    }
    red[threadIdx.x] = sum;
    __syncthreads();
    for (int s = 128; s > 0; s >>= 1) {
        if (threadIdx.x < s) red[threadIdx.x] += red[threadIdx.x + s];
        __syncthreads();
    }
    if (threadIdx.x == 0) out[0] = red[0] / (float)BSZ;
}

extern "C" void kernel_launch(void* const* d_in, const int* in_sizes, int n_in,
                              void* d_out, int out_size, void* d_ws, size_t ws_size,
                              hipStream_t stream) {
    const float* feat = (const float*)d_in[0];
    const float* va   = (const float*)d_in[1];
    const int*   dia  = (const int*)d_in[2];
    const int*   thr  = (const int*)d_in[3];

    unsigned short* con = (unsigned short*)d_ws;
    float* acc = (float*)((char*)d_ws + (size_t)NCON * DFEAT * 2);
    float* out = (float*)d_out;

    k_prep<<<(NCON * DFEAT / 4 + 255) / 256, 256, 0, stream>>>(feat, con, acc);

    dim3 grid(NCON / BJ, BSZ / BI);
    k_main<<<grid, 256, 0, stream>>>((const __hip_bfloat16*)con, va, dia, thr,
                                     acc, acc + BSZ, acc + 2 * BSZ);

    k_final<<<1, 256, 0, stream>>>(acc, acc + BSZ, acc + 2 * BSZ, out);
}

// Round 9
// 66.016 us; speedup vs baseline: 1.0995x; 1.0995x over previous
//
#include <hip/hip_runtime.h>
#include <hip/hip_bf16.h>

#define BSZ   4096
#define NCON  8192
#define DFEAT 256
#define C2    20.60992914f    // (1/0.07) * log2(e) : logits-minus-max in log2 units
#define LN2   0.6931471806f

#define BJ 64    // block tile in j (contrast) — staged in LDS
#define BI 128   // block tile in i (anchor) — 4 waves x 32 rows, in registers

typedef __attribute__((ext_vector_type(8))) short short8;
typedef __attribute__((ext_vector_type(4))) float f32x4;

__device__ __forceinline__ unsigned short f2bf(float f) {
    __hip_bfloat16 h = __float2bfloat16(f);
    return *reinterpret_cast<unsigned short*>(&h);
}

__device__ __forceinline__ void gload_lds16(const void* g, void* l) {
    __builtin_amdgcn_global_load_lds(
        (const __attribute__((address_space(1))) unsigned int*)g,
        (__attribute__((address_space(3))) unsigned int*)l,
        16, 0, 0);
}

// Volatile asm load: cannot be rematerialized/sunk by the scheduler — forces
// the result to stay register-resident. Result valid only after vmcnt drain
// (the __syncthreads() before first use emits s_waitcnt vmcnt(0)).
__device__ __forceinline__ void gload_reg16(const void* p, short8& dst) {
    unsigned long long a = (unsigned long long)p;
    asm volatile("global_load_dwordx4 %0, %1, off"
                 : "=v"(dst) : "v"(a));
}

// ws layout: [0, 4MB) contrast bf16 [NCON][DFEAT]; then f32 S[4096], A[4096], B[4096]

__global__ __launch_bounds__(256) void k_prep(const float* __restrict__ feat,
                                              unsigned short* __restrict__ con,
                                              float* __restrict__ acc) {
    int idx = blockIdx.x * 256 + threadIdx.x;
    int e = idx * 4;
    int j = e >> 8;
    int k = e & 255;
    int src = (j < BSZ) ? ((j * 2) * DFEAT + k)
                        : (((j - BSZ) * 2 + 1) * DFEAT + k);
    float4 f = *(const float4*)(feat + src);
    ushort4 o;
    o.x = f2bf(f.x); o.y = f2bf(f.y); o.z = f2bf(f.z); o.w = f2bf(f.w);
    *(ushort4*)(con + e) = o;
    if (idx < 3 * BSZ) acc[idx] = 0.0f;
}

// lX layout: 4 sub-panels [k2][row 0..63][64 cols], 128B row stride (0-conflict verified).
__global__ __launch_bounds__(256, 2) void k_main(const __hip_bfloat16* __restrict__ conp,
                                                 const float* __restrict__ va,
                                                 const int* __restrict__ dia,
                                                 const int* __restrict__ thr_ptr,
                                                 float* __restrict__ Srow,
                                                 float* __restrict__ Arow,
                                                 float* __restrict__ Brow) {
    __shared__ short lX[BJ * DFEAT];            // 32 KB total
    __shared__ float s_vjx[BJ], s_vjy[BJ];
    __shared__ int   s_dj[BJ];

    const int tid  = threadIdx.x;
    const int lane = tid & 63;
    const int wv   = tid >> 6;
    const int l15  = lane & 15;
    const int hi   = lane >> 4;
    const int jbase = blockIdx.x * BJ;              // [0, 8192)
    const int ibase = blockIdx.y * BI + wv * 32;    // this wave's 32 anchor rows
    const short* cs = (const short*)conp;

    // ---- stage X panel: linear LDS dest, inverse-swizzled global source ----
    #pragma unroll
    for (int q = 0; q < 8; ++q) {
        int e   = q * 2048 + tid * 8;      // element in [0, 16384)
        int col = e & 63;
        int row = (e >> 6) & 63;
        int k2  = e >> 12;                 // which 64-col sub-panel
        int scol = col ^ ((row & 7) << 3); // element-space involution (8-elem granules)
        gload_lds16(cs + (size_t)(jbase + row) * DFEAT + k2 * 64 + scol, &lX[e]);
    }

    // ---- Y panel to registers via volatile asm (64 VGPRs, guaranteed resident) ----
    const short* yrow0 = cs + (size_t)(ibase + l15) * DFEAT + hi * 8;
    short8 y[2][8];
    #pragma unroll
    for (int n = 0; n < 2; ++n)
        #pragma unroll
        for (int s = 0; s < 8; ++s)
            gload_reg16(yrow0 + (size_t)n * 16 * DFEAT + s * 32, y[n][s]);

    if (tid < BJ) {
        int jm = (jbase + tid) & (BSZ - 1);
        s_vjx[tid] = va[2 * jm]; s_vjy[tid] = va[2 * jm + 1]; s_dj[tid] = dia[jm];
    }

    int raw = *thr_ptr;
    float t_ = (raw > 0 && raw < 100000) ? (float)raw : __int_as_float(raw);
    float thres2 = t_ * t_;

    f32x4 acc[4][2];   // [m = j-frag][n = i-frag]
    #pragma unroll
    for (int m = 0; m < 4; ++m)
        #pragma unroll
        for (int n = 0; n < 2; ++n)
            acc[m][n] = (f32x4){0.f, 0.f, 0.f, 0.f};

    __syncthreads();   // emits s_waitcnt vmcnt(0): drains staging AND the asm Y loads
    asm volatile("s_waitcnt vmcnt(0)" ::: "memory");   // belt-and-suspenders
    __builtin_amdgcn_sched_barrier(0);

    // ---- straight-line K stream: 8 steps x (4 ds_read_b128 + 8 MFMA), no syncs ----
    #pragma unroll
    for (int s = 0; s < 8; ++s) {
        const int base = (s >> 1) * 8192;                    // sub-panel byte base
        const int colb = (s & 1) * 64 + hi * 16;             // byte col in sub-panel
        short8 xf[4];
        #pragma unroll
        for (int m = 0; m < 4; ++m) {
            int row = m * 16 + l15;
            xf[m] = *(const short8*)((const char*)lX + base + row * 128 + (colb ^ ((row & 7) << 4)));
        }
        #pragma unroll
        for (int m = 0; m < 4; ++m)
            #pragma unroll
            for (int n = 0; n < 2; ++n)
                acc[m][n] = __builtin_amdgcn_mfma_f32_16x16x32_bf16(xf[m], y[n][s], acc[m][n], 0, 0, 0);
    }

    // ---- epilogue: D[j][i]; lane holds j = m*16 + hi*4 + r, i = n*16 + l15 ----
    float vix[2], viy[2]; int di[2];
    #pragma unroll
    for (int n = 0; n < 2; ++n) {
        int i = ibase + n * 16 + l15;
        vix[n] = va[2 * i]; viy[n] = va[2 * i + 1]; di[n] = dia[i];
    }

    float sp[2] = {0.f, 0.f};
    float ap[2] = {0.f, 0.f};   // accumulated in log2 units
    float bp[2] = {0.f, 0.f};

    #pragma unroll
    for (int m = 0; m < 4; ++m) {
        #pragma unroll
        for (int r = 0; r < 4; ++r) {
            const int jl = m * 16 + hi * 4 + r;
            const int j  = jbase + jl;
            const int jm = j & (BSZ - 1);
            float vjx = s_vjx[jl], vjy = s_vjy[jl];
            int dj = s_dj[jl];
            #pragma unroll
            for (int n = 0; n < 2; ++n) {
                const int i = ibase + n * 16 + l15;
                float l2 = __builtin_fmaf(acc[m][n][r], C2, -C2);   // (dot-1)/T in log2
                bool lm = (j != i);
                float e = lm ? exp2f(l2) : 0.0f;
                float dx = vix[n] - vjx, dy = viy[n] - vjy;
                bool mk = (i == jm) | (di[n] == dj) | (dx * dx + dy * dy < thres2);
                sp[n] += e;
                if (mk & lm) { ap[n] += l2; bp[n] += 1.0f; }
            }
        }
    }

    #pragma unroll
    for (int n = 0; n < 2; ++n) {
        float s = sp[n], a = ap[n], b = bp[n];
        s += __shfl_xor(s, 16, 64);  a += __shfl_xor(a, 16, 64);  b += __shfl_xor(b, 16, 64);
        s += __shfl_xor(s, 32, 64);  a += __shfl_xor(a, 32, 64);  b += __shfl_xor(b, 32, 64);
        if (hi == 0) {
            int i = ibase + n * 16 + l15;
            atomicAdd(&Srow[i], s);
            atomicAdd(&Arow[i], a * LN2);   // back to natural-log units
            atomicAdd(&Brow[i], b);
        }
    }
}

__global__ __launch_bounds__(256) void k_final(const float* __restrict__ S,
                                               const float* __restrict__ A,
                                               const float* __restrict__ B,
                                               float* __restrict__ out) {
    __shared__ float red[256];
    float sum = 0.f;
    for (int i = threadIdx.x; i < BSZ; i += 256) {
        float b = B[i];
        float v = (A[i] - b * logf(S[i] + 1e-10f)) / (b + 1e-10f);
        sum += -v;
    }
    red[threadIdx.x] = sum;
    __syncthreads();
    for (int s = 128; s > 0; s >>= 1) {
        if (threadIdx.x < s) red[threadIdx.x] += red[threadIdx.x + s];
        __syncthreads();
    }
    if (threadIdx.x == 0) out[0] = red[0] / (float)BSZ;
}

extern "C" void kernel_launch(void* const* d_in, const int* in_sizes, int n_in,
                              void* d_out, int out_size, void* d_ws, size_t ws_size,
                              hipStream_t stream) {
    const float* feat = (const float*)d_in[0];
    const float* va   = (const float*)d_in[1];
    const int*   dia  = (const int*)d_in[2];
    const int*   thr  = (const int*)d_in[3];

    unsigned short* con = (unsigned short*)d_ws;
    float* acc = (float*)((char*)d_ws + (size_t)NCON * DFEAT * 2);
    float* out = (float*)d_out;

    k_prep<<<(NCON * DFEAT / 4 + 255) / 256, 256, 0, stream>>>(feat, con, acc);

    dim3 grid(NCON / BJ, BSZ / BI);
    k_main<<<grid, 256, 0, stream>>>((const __hip_bfloat16*)con, va, dia, thr,
                                     acc, acc + BSZ, acc + 2 * BSZ);

    k_final<<<1, 256, 0, stream>>>(acc, acc + BSZ, acc + 2 * BSZ, out);
}

// Round 10
// 48.655 us; speedup vs baseline: 1.4918x; 1.3568x over previous
//
#include <hip/hip_runtime.h>
#include <hip/hip_bf16.h>

#define BSZ   4096
#define NCON  8192
#define DFEAT 256
#define INV_T 14.285714285714285f   // 1/T; analytic row max (self-dot==1) folded in

#define BJ 64                 // j-tile width (per LDS panel)
#define BI 128                // i-rows per block (4 waves x 32)
#define NJT 8                 // j-tiles per block
#define JSTRIP (NJT * BJ)     // 512 contrast cols per block

typedef __attribute__((ext_vector_type(8))) short short8;
typedef __attribute__((ext_vector_type(4))) float f32x4;

__device__ __forceinline__ unsigned short f2bf(float f) {
    __hip_bfloat16 h = __float2bfloat16(f);
    return *reinterpret_cast<unsigned short*>(&h);
}

__device__ __forceinline__ void gload_lds16(const void* g, void* l) {
    __builtin_amdgcn_global_load_lds(
        (const __attribute__((address_space(1))) unsigned int*)g,
        (__attribute__((address_space(3))) unsigned int*)l,
        16, 0, 0);
}

// Volatile asm load: cannot be rematerialized/sunk — keeps Y register/AGPR-resident.
__device__ __forceinline__ void gload_reg16(const void* p, short8& dst) {
    unsigned long long a = (unsigned long long)p;
    asm volatile("global_load_dwordx4 %0, %1, off"
                 : "=v"(dst) : "v"(a));
}

// ws layout: [0, 4MB) contrast bf16 [NCON][DFEAT]; then f32 S[4096], A[4096], B[4096]

__global__ __launch_bounds__(256) void k_prep(const float* __restrict__ feat,
                                              unsigned short* __restrict__ con,
                                              float* __restrict__ acc) {
    int idx = blockIdx.x * 256 + threadIdx.x;
    int e = idx * 4;
    int j = e >> 8;
    int k = e & 255;
    int src = (j < BSZ) ? ((j * 2) * DFEAT + k)
                        : (((j - BSZ) * 2 + 1) * DFEAT + k);
    float4 f = *(const float4*)(feat + src);
    ushort4 o;
    o.x = f2bf(f.x); o.y = f2bf(f.y); o.z = f2bf(f.z); o.w = f2bf(f.w);
    *(ushort4*)(con + e) = o;
    if (idx < 3 * BSZ) acc[idx] = 0.0f;
}

// lX panels: 4 sub-panels [k2][row 0..63][64 cols], 128B row stride (0-conflict verified).
__global__ __launch_bounds__(256, 2) void k_main(const __hip_bfloat16* __restrict__ conp,
                                                 const float* __restrict__ va,
                                                 const int* __restrict__ dia,
                                                 const int* __restrict__ thr_ptr,
                                                 float* __restrict__ Srow,
                                                 float* __restrict__ Arow,
                                                 float* __restrict__ Brow) {
    __shared__ short lX[2][BJ * DFEAT];          // 2 x 32 KB, double-buffered
    __shared__ float s_vjx[JSTRIP], s_vjy[JSTRIP];
    __shared__ int   s_dj[JSTRIP];

    const int tid  = threadIdx.x;
    const int lane = tid & 63;
    const int wv   = tid >> 6;
    const int l15  = lane & 15;
    const int hi   = lane >> 4;
    const int jstrip0 = blockIdx.x * JSTRIP;        // [0, 8192)
    const int ibase   = blockIdx.y * BI + wv * 32;  // this wave's 32 anchor rows
    const short* cs = (const short*)conp;

    auto stageX = [&](int buf, int jt) {
        #pragma unroll
        for (int q = 0; q < 8; ++q) {
            int e   = q * 2048 + tid * 8;      // element in [0, 16384)
            int col = e & 63;
            int row = (e >> 6) & 63;
            int k2  = e >> 12;                 // 64-col sub-panel
            int scol = col ^ ((row & 7) << 3); // involution pre-swizzle
            gload_lds16(cs + (size_t)(jstrip0 + jt * BJ + row) * DFEAT + k2 * 64 + scol,
                        &lX[buf][e]);
        }
    };

    stageX(0, 0);

    // ---- Y panel to registers (volatile asm; 64 regs, resident) ----
    const short* yrow0 = cs + (size_t)(ibase + l15) * DFEAT + hi * 8;
    short8 y[2][8];
    #pragma unroll
    for (int n = 0; n < 2; ++n)
        #pragma unroll
        for (int s = 0; s < 8; ++s)
            gload_reg16(yrow0 + (size_t)n * 16 * DFEAT + s * 32, y[n][s]);

    // ---- strip metadata (512 j entries) ----
    for (int c = tid; c < JSTRIP; c += 256) {
        int jm = (jstrip0 + c) & (BSZ - 1);
        s_vjx[c] = va[2 * jm]; s_vjy[c] = va[2 * jm + 1]; s_dj[c] = dia[jm];
    }

    int raw = *thr_ptr;
    float t_ = (raw > 0 && raw < 100000) ? (float)raw : __int_as_float(raw);
    float thres2 = t_ * t_;

    float vix[2], viy[2]; int di[2];
    #pragma unroll
    for (int n = 0; n < 2; ++n) {
        int i = ibase + n * 16 + l15;
        vix[n] = va[2 * i]; viy[n] = va[2 * i + 1]; di[n] = dia[i];
    }

    float sp[2] = {0.f, 0.f};
    float ap[2] = {0.f, 0.f};
    float bp[2] = {0.f, 0.f};

    __syncthreads();                                   // drains staging + Y loads
    asm volatile("s_waitcnt vmcnt(0)" ::: "memory");
    __builtin_amdgcn_sched_barrier(0);

    for (int jt = 0; jt < NJT; ++jt) {
        const int cur = jt & 1;
        if (jt < NJT - 1) stageX(cur ^ 1, jt + 1);     // stream next tile under compute

        f32x4 acc[4][2];
        #pragma unroll
        for (int m = 0; m < 4; ++m)
            #pragma unroll
            for (int n = 0; n < 2; ++n)
                acc[m][n] = (f32x4){0.f, 0.f, 0.f, 0.f};

        const char* bufX = (const char*)&lX[cur][0];
        #pragma unroll
        for (int s = 0; s < 8; ++s) {
            const int base = (s >> 1) * 8192;          // sub-panel byte base
            const int colb = (s & 1) * 64 + hi * 16;   // byte col in sub-panel
            short8 xf[4];
            #pragma unroll
            for (int m = 0; m < 4; ++m) {
                int row = m * 16 + l15;
                xf[m] = *(const short8*)(bufX + base + row * 128 + (colb ^ ((row & 7) << 4)));
            }
            #pragma unroll
            for (int m = 0; m < 4; ++m)
                #pragma unroll
                for (int n = 0; n < 2; ++n)
                    acc[m][n] = __builtin_amdgcn_mfma_f32_16x16x32_bf16(xf[m], y[n][s], acc[m][n], 0, 0, 0);
        }

        // epilogue for this tile: registers + loop-invariant LDS metadata only
        const int jt0 = jt * BJ;
        #pragma unroll
        for (int m = 0; m < 4; ++m) {
            #pragma unroll
            for (int r = 0; r < 4; ++r) {
                const int jl = m * 16 + hi * 4 + r;
                const int j  = jstrip0 + jt0 + jl;
                const int jm = j & (BSZ - 1);
                float vjx = s_vjx[jt0 + jl], vjy = s_vjy[jt0 + jl];
                int dj = s_dj[jt0 + jl];
                #pragma unroll
                for (int n = 0; n < 2; ++n) {
                    const int i = ibase + n * 16 + l15;
                    float l = __builtin_fmaf(acc[m][n][r], INV_T, -INV_T);  // logits - max
                    bool lm = (j != i);
                    float e = lm ? __expf(l) : 0.0f;                        // native v_exp
                    float dx = vix[n] - vjx, dy = viy[n] - vjy;
                    bool mk = (i == jm) | (di[n] == dj) | (dx * dx + dy * dy < thres2);
                    sp[n] += e;
                    if (mk & lm) { ap[n] += l; bp[n] += 1.0f; }
                }
            }
        }
        __syncthreads();   // next iter may overwrite buf; also drains this iter's stage
    }

    // ---- one reduction + atomic set per block ----
    #pragma unroll
    for (int n = 0; n < 2; ++n) {
        float s = sp[n], a = ap[n], b = bp[n];
        s += __shfl_xor(s, 16, 64);  a += __shfl_xor(a, 16, 64);  b += __shfl_xor(b, 16, 64);
        s += __shfl_xor(s, 32, 64);  a += __shfl_xor(a, 32, 64);  b += __shfl_xor(b, 32, 64);
        if (hi == 0) {
            int i = ibase + n * 16 + l15;
            atomicAdd(&Srow[i], s);
            atomicAdd(&Arow[i], a);
            atomicAdd(&Brow[i], b);
        }
    }
}

__global__ __launch_bounds__(256) void k_final(const float* __restrict__ S,
                                               const float* __restrict__ A,
                                               const float* __restrict__ B,
                                               float* __restrict__ out) {
    __shared__ float red[256];
    float sum = 0.f;
    for (int i = threadIdx.x; i < BSZ; i += 256) {
        float b = B[i];
        float v = (A[i] - b * logf(S[i] + 1e-10f)) / (b + 1e-10f);
        sum += -v;
    }
    red[threadIdx.x] = sum;
    __syncthreads();
    for (int s = 128; s > 0; s >>= 1) {
        if (threadIdx.x < s) red[threadIdx.x] += red[threadIdx.x + s];
        __syncthreads();
    }
    if (threadIdx.x == 0) out[0] = red[0] / (float)BSZ;
}

extern "C" void kernel_launch(void* const* d_in, const int* in_sizes, int n_in,
                              void* d_out, int out_size, void* d_ws, size_t ws_size,
                              hipStream_t stream) {
    const float* feat = (const float*)d_in[0];
    const float* va   = (const float*)d_in[1];
    const int*   dia  = (const int*)d_in[2];
    const int*   thr  = (const int*)d_in[3];

    unsigned short* con = (unsigned short*)d_ws;
    float* acc = (float*)((char*)d_ws + (size_t)NCON * DFEAT * 2);
    float* out = (float*)d_out;

    k_prep<<<(NCON * DFEAT / 4 + 255) / 256, 256, 0, stream>>>(feat, con, acc);

    dim3 grid(NCON / JSTRIP, BSZ / BI);   // (16, 32) = 512 blocks = 2/CU
    k_main<<<grid, 256, 0, stream>>>((const __hip_bfloat16*)con, va, dia, thr,
                                     acc, acc + BSZ, acc + 2 * BSZ);

    k_final<<<1, 256, 0, stream>>>(acc, acc + BSZ, acc + 2 * BSZ, out);
}

// Round 11
// 48.565 us; speedup vs baseline: 1.4946x; 1.0019x over previous
//
#include <hip/hip_runtime.h>
#include <hip/hip_bf16.h>

#define BSZ   4096
#define NCON  8192
#define DFEAT 256
#define INV_T 14.285714285714285f   // 1/T; analytic row max (self-dot==1) folded in

#define BJ 32                 // j-tile width (per LDS panel)
#define BI 128                // i-rows per block (4 waves x 32)
#define NJT 16                // j-tiles per block
#define JSTRIP (NJT * BJ)     // 512 contrast cols per block

typedef __attribute__((ext_vector_type(8))) short short8;
typedef __attribute__((ext_vector_type(4))) float f32x4;

__device__ __forceinline__ unsigned short f2bf(float f) {
    __hip_bfloat16 h = __float2bfloat16(f);
    return *reinterpret_cast<unsigned short*>(&h);
}

__device__ __forceinline__ void gload_lds16(const void* g, void* l) {
    __builtin_amdgcn_global_load_lds(
        (const __attribute__((address_space(1))) unsigned int*)g,
        (__attribute__((address_space(3))) unsigned int*)l,
        16, 0, 0);
}

// Volatile asm load: cannot be rematerialized/sunk — keeps Y register-resident.
__device__ __forceinline__ void gload_reg16(const void* p, short8& dst) {
    unsigned long long a = (unsigned long long)p;
    asm volatile("global_load_dwordx4 %0, %1, off"
                 : "=v"(dst) : "v"(a));
}

// ws layout: [0, 4MB) contrast bf16 [NCON][DFEAT]; then f32 S[4096], A[4096], B[4096]

__global__ __launch_bounds__(256) void k_prep(const float* __restrict__ feat,
                                              unsigned short* __restrict__ con,
                                              float* __restrict__ acc) {
    int idx = blockIdx.x * 256 + threadIdx.x;
    int e = idx * 4;
    int j = e >> 8;
    int k = e & 255;
    int src = (j < BSZ) ? ((j * 2) * DFEAT + k)
                        : (((j - BSZ) * 2 + 1) * DFEAT + k);
    float4 f = *(const float4*)(feat + src);
    ushort4 o;
    o.x = f2bf(f.x); o.y = f2bf(f.y); o.z = f2bf(f.z); o.w = f2bf(f.w);
    *(ushort4*)(con + e) = o;
    if (idx < 3 * BSZ) acc[idx] = 0.0f;
}

// lX panel (16 KB): 4 sub-panels [k2][row 0..31][64 cols], 128B row stride —
// same row-stride/swizzle pattern that measured 0 bank conflicts.
__global__ __launch_bounds__(256, 2) void k_main(const __hip_bfloat16* __restrict__ conp,
                                                 const float* __restrict__ va,
                                                 const int* __restrict__ dia,
                                                 const int* __restrict__ thr_ptr,
                                                 float* __restrict__ Srow,
                                                 float* __restrict__ Arow,
                                                 float* __restrict__ Brow) {
    __shared__ short lX[2][BJ * DFEAT];          // 2 x 16 KB, double-buffered
    __shared__ float s_vjx[JSTRIP], s_vjy[JSTRIP];
    __shared__ int   s_dj[JSTRIP];

    const int tid  = threadIdx.x;
    const int lane = tid & 63;
    const int wv   = tid >> 6;
    const int l15  = lane & 15;
    const int hi   = lane >> 4;
    const int jstrip0 = blockIdx.x * JSTRIP;        // [0, 8192)
    const int ibase   = blockIdx.y * BI + wv * 32;  // this wave's 32 anchor rows
    const short* cs = (const short*)conp;

    auto stageX = [&](int buf, int jt) {
        #pragma unroll
        for (int q = 0; q < 4; ++q) {
            int e   = q * 2048 + tid * 8;      // element in [0, 8192)
            int col = e & 63;
            int row = (e >> 6) & 31;
            int k2  = e >> 11;                 // 64-col sub-panel (0..3)
            int scol = col ^ ((row & 7) << 3); // involution pre-swizzle
            gload_lds16(cs + (size_t)(jstrip0 + jt * BJ + row) * DFEAT + k2 * 64 + scol,
                        &lX[buf][e]);
        }
    };

    stageX(0, 0);

    // ---- Y panel to registers (volatile asm; 64 regs, resident) ----
    const short* yrow0 = cs + (size_t)(ibase + l15) * DFEAT + hi * 8;
    short8 y[2][8];
    #pragma unroll
    for (int n = 0; n < 2; ++n)
        #pragma unroll
        for (int s = 0; s < 8; ++s)
            gload_reg16(yrow0 + (size_t)n * 16 * DFEAT + s * 32, y[n][s]);

    // ---- strip metadata (512 j entries) ----
    for (int c = tid; c < JSTRIP; c += 256) {
        int jm = (jstrip0 + c) & (BSZ - 1);
        s_vjx[c] = va[2 * jm]; s_vjy[c] = va[2 * jm + 1]; s_dj[c] = dia[jm];
    }

    int raw = *thr_ptr;
    float t_ = (raw > 0 && raw < 100000) ? (float)raw : __int_as_float(raw);
    float thres2 = t_ * t_;

    float vix[2], viy[2]; int di[2];
    #pragma unroll
    for (int n = 0; n < 2; ++n) {
        int i = ibase + n * 16 + l15;
        vix[n] = va[2 * i]; viy[n] = va[2 * i + 1]; di[n] = dia[i];
    }

    float sp[2] = {0.f, 0.f};
    float ap[2] = {0.f, 0.f};
    float bp[2] = {0.f, 0.f};

    __syncthreads();                                   // drains staging + Y loads
    asm volatile("s_waitcnt vmcnt(0)" ::: "memory");
    __builtin_amdgcn_sched_barrier(0);

    for (int jt = 0; jt < NJT; ++jt) {
        const int cur = jt & 1;
        if (jt < NJT - 1) stageX(cur ^ 1, jt + 1);     // stream next tile under compute

        f32x4 acc[2][2];
        #pragma unroll
        for (int m = 0; m < 2; ++m)
            #pragma unroll
            for (int n = 0; n < 2; ++n)
                acc[m][n] = (f32x4){0.f, 0.f, 0.f, 0.f};

        const char* bufX = (const char*)&lX[cur][0];
        #pragma unroll
        for (int s = 0; s < 8; ++s) {
            const int base = (s >> 1) * 4096;          // sub-panel byte base (32x128B)
            const int colb = (s & 1) * 64 + hi * 16;   // byte col in sub-panel
            short8 xf[2];
            #pragma unroll
            for (int m = 0; m < 2; ++m) {
                int row = m * 16 + l15;
                xf[m] = *(const short8*)(bufX + base + row * 128 + (colb ^ ((row & 7) << 4)));
            }
            #pragma unroll
            for (int m = 0; m < 2; ++m)
                #pragma unroll
                for (int n = 0; n < 2; ++n)
                    acc[m][n] = __builtin_amdgcn_mfma_f32_16x16x32_bf16(xf[m], y[n][s], acc[m][n], 0, 0, 0);
        }

        // epilogue for this tile: registers + loop-invariant LDS metadata only
        const int jt0 = jt * BJ;
        #pragma unroll
        for (int m = 0; m < 2; ++m) {
            #pragma unroll
            for (int r = 0; r < 4; ++r) {
                const int jl = m * 16 + hi * 4 + r;
                const int j  = jstrip0 + jt0 + jl;
                const int jm = j & (BSZ - 1);
                float vjx = s_vjx[jt0 + jl], vjy = s_vjy[jt0 + jl];
                int dj = s_dj[jt0 + jl];
                #pragma unroll
                for (int n = 0; n < 2; ++n) {
                    const int i = ibase + n * 16 + l15;
                    float l = __builtin_fmaf(acc[m][n][r], INV_T, -INV_T);  // logits - max
                    bool lm = (j != i);
                    float e = lm ? __expf(l) : 0.0f;                        // native v_exp
                    float dx = vix[n] - vjx, dy = viy[n] - vjy;
                    bool mk = (i == jm) | (di[n] == dj) | (dx * dx + dy * dy < thres2);
                    sp[n] += e;
                    if (mk & lm) { ap[n] += l; bp[n] += 1.0f; }
                }
            }
        }
        __syncthreads();   // next iter overwrites cur^1's partner; drains stage
    }

    // ---- one reduction + atomic set per block ----
    #pragma unroll
    for (int n = 0; n < 2; ++n) {
        float s = sp[n], a = ap[n], b = bp[n];
        s += __shfl_xor(s, 16, 64);  a += __shfl_xor(a, 16, 64);  b += __shfl_xor(b, 16, 64);
        s += __shfl_xor(s, 32, 64);  a += __shfl_xor(a, 32, 64);  b += __shfl_xor(b, 32, 64);
        if (hi == 0) {
            int i = ibase + n * 16 + l15;
            atomicAdd(&Srow[i], s);
            atomicAdd(&Arow[i], a);
            atomicAdd(&Brow[i], b);
        }
    }
}

__global__ __launch_bounds__(256) void k_final(const float* __restrict__ S,
                                               const float* __restrict__ A,
                                               const float* __restrict__ B,
                                               float* __restrict__ out) {
    __shared__ float red[256];
    float sum = 0.f;
    for (int i = threadIdx.x; i < BSZ; i += 256) {
        float b = B[i];
        float v = (A[i] - b * logf(S[i] + 1e-10f)) / (b + 1e-10f);
        sum += -v;
    }
    red[threadIdx.x] = sum;
    __syncthreads();
    for (int s = 128; s > 0; s >>= 1) {
        if (threadIdx.x < s) red[threadIdx.x] += red[threadIdx.x + s];
        __syncthreads();
    }
    if (threadIdx.x == 0) out[0] = red[0] / (float)BSZ;
}

extern "C" void kernel_launch(void* const* d_in, const int* in_sizes, int n_in,
                              void* d_out, int out_size, void* d_ws, size_t ws_size,
                              hipStream_t stream) {
    const float* feat = (const float*)d_in[0];
    const float* va   = (const float*)d_in[1];
    const int*   dia  = (const int*)d_in[2];
    const int*   thr  = (const int*)d_in[3];

    unsigned short* con = (unsigned short*)d_ws;
    float* acc = (float*)((char*)d_ws + (size_t)NCON * DFEAT * 2);
    float* out = (float*)d_out;

    k_prep<<<(NCON * DFEAT / 4 + 255) / 256, 256, 0, stream>>>(feat, con, acc);

    dim3 grid(NCON / JSTRIP, BSZ / BI);   // (16, 32) = 512 blocks
    k_main<<<grid, 256, 0, stream>>>((const __hip_bfloat16*)con, va, dia, thr,
                                     acc, acc + BSZ, acc + 2 * BSZ);

    k_final<<<1, 256, 0, stream>>>(acc, acc + BSZ, acc + 2 * BSZ, out);
}